// Round 3
// baseline (283.939 us; speedup 1.0000x reference)
//
#include <hip/hip_runtime.h>

// Ranking-loss scalar reduction:
//   loss = 0.2 * (pos*sum_neg - neg*sum_pos) / (pos*neg)
// Needs sum(y), sum(y*lab), sum(lab) over N=32M floats/ints (256 MB read).
//
// R1 lesson: same-address fp64 atomics serialize (~45us penalty) -> per-block
// partial stores + stage2.
// R2 lesson: grid-stride + 4-loads-then-vmcnt(0) + serial fp64 chain = only
// 2.6 TB/s (VALUBusy 6.6%, nothing busy -> latency/MLP bound). This version:
// contiguous per-block chunks (DRAM row locality), 8 independent loads in
// flight per wave, and fp32 partials promoted to fp64 once per 16 elements
// (kills the dependent f64 chain; loss error ~1e-11 vs 6e-7 threshold).

#define NBLK 2048
#define TPB 256
#define UNROLL 4

__global__ __launch_bounds__(TPB, 8)
void aux_loss_reduce(const float* __restrict__ y,
                     const int* __restrict__ lab,
                     double* __restrict__ part, int n) {
    const int n4 = n >> 2;
    const float4* __restrict__ y4 = (const float4*)y;
    const int4* __restrict__ l4 = (const int4*)lab;

    // contiguous chunk per block
    const int chunk = (n4 + NBLK - 1) / NBLK;          // 4096 for N=32M
    const int base = blockIdx.x * chunk;
    const int end = min(base + chunk, n4);

    double s_all = 0.0, s_pos = 0.0;
    long long cnt = 0;

    for (int i0 = base; i0 < end; i0 += TPB * UNROLL) {
        float4 v[UNROLL];
        int4 l[UNROLL];
        // issue all 8 loads back-to-back (independent, contiguous 16KB block)
#pragma unroll
        for (int u = 0; u < UNROLL; ++u) {
            const int i = i0 + u * TPB + (int)threadIdx.x;
            const bool ok = i < end;
            v[u] = ok ? y4[i] : make_float4(0.f, 0.f, 0.f, 0.f);
            l[u] = ok ? l4[i] : make_int4(0, 0, 0, 0);
        }
        // fp32 partial over 16 elements (error ~1e-6 -> loss error ~1e-11)
        float pa = 0.f, pp = 0.f;
        int pc = 0;
#pragma unroll
        for (int u = 0; u < UNROLL; ++u) {
            pa += (v[u].x + v[u].y) + (v[u].z + v[u].w);
            const float mx = l[u].x ? v[u].x : 0.f;
            const float my = l[u].y ? v[u].y : 0.f;
            const float mz = l[u].z ? v[u].z : 0.f;
            const float mw = l[u].w ? v[u].w : 0.f;
            pp += (mx + my) + (mz + mw);
            pc += l[u].x + l[u].y + l[u].z + l[u].w;
        }
        s_all += (double)pa;
        s_pos += (double)pp;
        cnt += pc;
    }

    // scalar tail (n % 4 elements) — block 0 only
    if (blockIdx.x == 0) {
        for (int j = (n4 << 2) + (int)threadIdx.x; j < n; j += TPB) {
            const float v = y[j];
            const int l = lab[j];
            s_all += (double)v;
            if (l) { s_pos += (double)v; cnt += l; }
        }
    }

    double c = (double)cnt;

    // wave-level reduce (64 lanes)
    for (int off = 32; off > 0; off >>= 1) {
        s_all += __shfl_down(s_all, off);
        s_pos += __shfl_down(s_pos, off);
        c     += __shfl_down(c, off);
    }

    // cross-wave via LDS (256-thread block = 4 waves)
    __shared__ double sh_all[4], sh_pos[4], sh_cnt[4];
    const int wave = threadIdx.x >> 6;
    const int lane = threadIdx.x & 63;
    if (lane == 0) { sh_all[wave] = s_all; sh_pos[wave] = s_pos; sh_cnt[wave] = c; }
    __syncthreads();

    if (threadIdx.x == 0) {
        double a = 0.0, p = 0.0, cc = 0.0;
        for (int w = 0; w < 4; ++w) { a += sh_all[w]; p += sh_pos[w]; cc += sh_cnt[w]; }
        // SoA partials: contention-free plain stores, coalesced stage-2 reads
        part[blockIdx.x]            = a;
        part[NBLK + blockIdx.x]     = p;
        part[2 * NBLK + blockIdx.x] = cc;
    }
}

__global__ void aux_loss_stage2(const double* __restrict__ part,
                                float* __restrict__ out, double n_total) {
    double a = 0.0, p = 0.0, cc = 0.0;
    for (int i = threadIdx.x; i < NBLK; i += blockDim.x) {
        a  += part[i];
        p  += part[NBLK + i];
        cc += part[2 * NBLK + i];
    }
    for (int off = 32; off > 0; off >>= 1) {
        a  += __shfl_down(a, off);
        p  += __shfl_down(p, off);
        cc += __shfl_down(cc, off);
    }
    __shared__ double sh_a[4], sh_p[4], sh_c[4];
    const int wave = threadIdx.x >> 6;
    const int lane = threadIdx.x & 63;
    if (lane == 0) { sh_a[wave] = a; sh_p[wave] = p; sh_c[wave] = cc; }
    __syncthreads();

    if (threadIdx.x == 0) {
        double sum_all = 0.0, sum_pos = 0.0, pos = 0.0;
        for (int w = 0; w < 4; ++w) { sum_all += sh_a[w]; sum_pos += sh_p[w]; pos += sh_c[w]; }
        const double neg = n_total - pos;
        const double sum_neg = sum_all - sum_pos;
        double loss = 0.0;
        if (pos > 0.0 && neg > 0.0) {
            loss = 0.2 * (pos * sum_neg - neg * sum_pos) / (pos * neg);
        }
        out[0] = (float)loss;
    }
}

extern "C" void kernel_launch(void* const* d_in, const int* in_sizes, int n_in,
                              void* d_out, int out_size, void* d_ws, size_t ws_size,
                              hipStream_t stream) {
    const float* y = (const float*)d_in[0];
    const int* lab = (const int*)d_in[1];
    int n = in_sizes[0];

    double* part = (double*)d_ws;  // 3 * NBLK doubles = 48 KB of scratch
    // No memset needed: every slot is unconditionally written by stage 1.

    aux_loss_reduce<<<NBLK, TPB, 0, stream>>>(y, lab, part, n);
    aux_loss_stage2<<<1, TPB, 0, stream>>>(part, (float*)d_out, (double)n);
}

// Round 4
// 250.436 us; speedup vs baseline: 1.1338x; 1.1338x over previous
//
#include <hip/hip_runtime.h>

// Ranking-loss scalar reduction:
//   loss = 0.2 * (pos*sum_neg - neg*sum_pos) / (pos*neg)
// Needs sum(y), sum(y*lab), sum(lab) over N=32M floats/ints (256 MB read).
//
// R1: same-address fp64 atomics serialize -> per-block partials + stage2.
// R2/R3: three different loop structures (grid-stride, chunked, 8-deep MLP)
// all pin at ~105us = 2.5 TB/s consumed, with VALUBusy ~6%, HBM at 1.25 TB/s
// (half the footprint L3-resident), occupancy ~65%. Neither HBM, L3, nor the
// CU front-end is saturated -> the shared limiter is the L2 allocate/fill
// path for a zero-reuse stream. R4 change: nontemporal loads (nt/sc bits on
// global_load_dwordx4) so L2 streams instead of allocating.
//
// fp64 accumulation of per-iteration fp32 partials: final expression is a
// catastrophic cancellation; fp32-partial error contributes ~1e-11 to the
// loss vs the 6e-7 harness threshold.

#define NBLK 2048
#define TPB 256
#define UNROLL 4

typedef float  f4 __attribute__((ext_vector_type(4)));
typedef int    i4 __attribute__((ext_vector_type(4)));

__global__ __launch_bounds__(TPB, 8)
void aux_loss_reduce(const float* __restrict__ y,
                     const int* __restrict__ lab,
                     double* __restrict__ part, int n) {
    const int n4 = n >> 2;
    const f4* __restrict__ y4 = (const f4*)y;
    const i4* __restrict__ l4 = (const i4*)lab;

    // contiguous chunk per block
    const int chunk = (n4 + NBLK - 1) / NBLK;          // 4096 for N=32M
    const int base = blockIdx.x * chunk;
    const int end = min(base + chunk, n4);
    const int span = TPB * UNROLL;
    const int nfull = (end - base) / span;             // full, bounds-check-free iters

    double s_all = 0.0, s_pos = 0.0;
    long long cnt = 0;

    int i0 = base;
    for (int it = 0; it < nfull; ++it, i0 += span) {
        f4 v[UNROLL];
        i4 l[UNROLL];
        // 8 independent nontemporal 16B loads in flight, contiguous 16KB block
#pragma unroll
        for (int u = 0; u < UNROLL; ++u) {
            const int i = i0 + u * TPB + (int)threadIdx.x;
            v[u] = __builtin_nontemporal_load(&y4[i]);
            l[u] = __builtin_nontemporal_load(&l4[i]);
        }
        float pa = 0.f, pp = 0.f;
        int pc = 0;
#pragma unroll
        for (int u = 0; u < UNROLL; ++u) {
            pa += (v[u].x + v[u].y) + (v[u].z + v[u].w);
            const float mx = l[u].x ? v[u].x : 0.f;
            const float my = l[u].y ? v[u].y : 0.f;
            const float mz = l[u].z ? v[u].z : 0.f;
            const float mw = l[u].w ? v[u].w : 0.f;
            pp += (mx + my) + (mz + mw);
            pc += l[u].x + l[u].y + l[u].z + l[u].w;
        }
        s_all += (double)pa;
        s_pos += (double)pp;
        cnt += pc;
    }
    // remainder iteration (bounds-checked) — no-op when chunk % span == 0
    for (int i = i0 + (int)threadIdx.x; i < end; i += TPB) {
        f4 v = __builtin_nontemporal_load(&y4[i]);
        i4 l = __builtin_nontemporal_load(&l4[i]);
        float pa = (v.x + v.y) + (v.z + v.w);
        float pp = (l.x ? v.x : 0.f) + (l.y ? v.y : 0.f)
                 + (l.z ? v.z : 0.f) + (l.w ? v.w : 0.f);
        s_all += (double)pa;
        s_pos += (double)pp;
        cnt += l.x + l.y + l.z + l.w;
    }

    // scalar tail (n % 4 elements) — block 0 only
    if (blockIdx.x == 0) {
        for (int j = (n4 << 2) + (int)threadIdx.x; j < n; j += TPB) {
            const float v = y[j];
            const int l = lab[j];
            s_all += (double)v;
            if (l) { s_pos += (double)v; cnt += l; }
        }
    }

    double c = (double)cnt;

    // wave-level reduce (64 lanes)
    for (int off = 32; off > 0; off >>= 1) {
        s_all += __shfl_down(s_all, off);
        s_pos += __shfl_down(s_pos, off);
        c     += __shfl_down(c, off);
    }

    // cross-wave via LDS (256-thread block = 4 waves)
    __shared__ double sh_all[4], sh_pos[4], sh_cnt[4];
    const int wave = threadIdx.x >> 6;
    const int lane = threadIdx.x & 63;
    if (lane == 0) { sh_all[wave] = s_all; sh_pos[wave] = s_pos; sh_cnt[wave] = c; }
    __syncthreads();

    if (threadIdx.x == 0) {
        double a = 0.0, p = 0.0, cc = 0.0;
        for (int w = 0; w < 4; ++w) { a += sh_all[w]; p += sh_pos[w]; cc += sh_cnt[w]; }
        // SoA partials: contention-free plain stores, coalesced stage-2 reads
        part[blockIdx.x]            = a;
        part[NBLK + blockIdx.x]     = p;
        part[2 * NBLK + blockIdx.x] = cc;
    }
}

__global__ void aux_loss_stage2(const double* __restrict__ part,
                                float* __restrict__ out, double n_total) {
    double a = 0.0, p = 0.0, cc = 0.0;
    for (int i = threadIdx.x; i < NBLK; i += blockDim.x) {
        a  += part[i];
        p  += part[NBLK + i];
        cc += part[2 * NBLK + i];
    }
    for (int off = 32; off > 0; off >>= 1) {
        a  += __shfl_down(a, off);
        p  += __shfl_down(p, off);
        cc += __shfl_down(cc, off);
    }
    __shared__ double sh_a[4], sh_p[4], sh_c[4];
    const int wave = threadIdx.x >> 6;
    const int lane = threadIdx.x & 63;
    if (lane == 0) { sh_a[wave] = a; sh_p[wave] = p; sh_c[wave] = cc; }
    __syncthreads();

    if (threadIdx.x == 0) {
        double sum_all = 0.0, sum_pos = 0.0, pos = 0.0;
        for (int w = 0; w < 4; ++w) { sum_all += sh_a[w]; sum_pos += sh_p[w]; pos += sh_c[w]; }
        const double neg = n_total - pos;
        const double sum_neg = sum_all - sum_pos;
        double loss = 0.0;
        if (pos > 0.0 && neg > 0.0) {
            loss = 0.2 * (pos * sum_neg - neg * sum_pos) / (pos * neg);
        }
        out[0] = (float)loss;
    }
}

extern "C" void kernel_launch(void* const* d_in, const int* in_sizes, int n_in,
                              void* d_out, int out_size, void* d_ws, size_t ws_size,
                              hipStream_t stream) {
    const float* y = (const float*)d_in[0];
    const int* lab = (const int*)d_in[1];
    int n = in_sizes[0];

    double* part = (double*)d_ws;  // 3 * NBLK doubles = 48 KB of scratch
    // No memset needed: every slot is unconditionally written by stage 1.

    aux_loss_reduce<<<NBLK, TPB, 0, stream>>>(y, lab, part, n);
    aux_loss_stage2<<<1, TPB, 0, stream>>>(part, (float*)d_out, (double)n);
}